// Round 6
// baseline (50.456 us; speedup 1.0000x reference)
//
#include <hip/hip_runtime.h>

// DynamicEdgeWeightLearner — v6: v5 + L2-residency protection + exact-grid path.
//   h1 = relu(W1a@x[row] + W1b@x[col] + b1),  W1 = [W1a | W1b]
// Precompute per node (MFMA): ya = x@W1a^T + b1, yb = x@W1b^T, int8 (scale
// 127/2). Tables 3.2 MB -> per-XCD-L2 resident. Per edge: gather qa/qb (8 B),
// h1 = relu((qa+qb)*s) -> bf16 B-frag, one swapped MFMA (C[ch][edge]),
// 2 shfl_xor reduce, coalesced 16-float store.
// v6 changes (latency x MSHR model: gather = 2 random L2 lines/edge,
// ~54-outstanding cap/CU):
//  - edge-index loads + output stores NONTEMPORAL (no-allocate): the 12.8 MB
//    index stream + 6.4 MB out stream were evicting table lines from the
//    4 MB/XCD L2, pushing gathers to L3 (~600 cyc). Gathers stay cached.
//  - EXACT template path (E % 256 == 0): no clamps, no tail selects, int32
//    address math.

typedef __attribute__((ext_vector_type(8))) short short8v;  // 8 x bf16
typedef __attribute__((ext_vector_type(8))) char  char8v;   // 8 x int8
typedef __attribute__((ext_vector_type(4))) float f32x4;    // MFMA C/D frag

#define QSCALE   63.5f           // 127 / 2.0
#define QDEQ     0.015748031f    // 1 / 63.5

__device__ __forceinline__ unsigned short f32_bf16(float f) {
    union { float f; unsigned u; } v; v.f = f;
    return (unsigned short)((v.u + 0x7fffu + ((v.u >> 16) & 1u)) >> 16);  // RTNE
}
__device__ __forceinline__ short8v conv8(const float* src) {
    f32x4 f0 = *(const f32x4*)src;
    f32x4 f1 = *(const f32x4*)(src + 4);
    short8v r;
#pragma unroll
    for (int j = 0; j < 4; ++j) {
        r[j]     = (short)f32_bf16(f0[j]);
        r[4 + j] = (short)f32_bf16(f1[j]);
    }
    return r;
}
__device__ __forceinline__ char q8(float y) {
    int q = __float2int_rn(y * QSCALE);
    q = q > 127 ? 127 : (q < -127 ? -127 : q);
    return (char)q;
}

// ---------------- precompute: int8 ya = x@W1a^T + b1, yb = x@W1b^T ----------
__global__ __launch_bounds__(256) void precompute_y(
    const float* __restrict__ x, const float* __restrict__ W1,
    const float* __restrict__ b1,
    char* __restrict__ ya, char* __restrict__ yb, int N)
{
    const int t = threadIdx.x;
    const int w = t >> 6, l = t & 63, n = l & 15, g = l >> 4;
    const long long base = ((long long)blockIdx.x * 4 + w) * 16;
    if (base >= N) return;

    short8v Bf[2][2][2];
#pragma unroll
    for (int s = 0; s < 2; ++s)
#pragma unroll
        for (int nt = 0; nt < 2; ++nt)
#pragma unroll
            for (int q = 0; q < 2; ++q)
                Bf[s][nt][q] = conv8(W1 + (nt * 16 + n) * 128 + s * 64 + q * 32 + g * 8);

    long long row = base + n; if (row > (long long)N - 1) row = N - 1;
    const float* xr = x + row * 64;
    short8v a0 = conv8(xr + g * 8);
    short8v a1 = conv8(xr + 32 + g * 8);

    const float bA0 = b1[n], bA1 = b1[16 + n];
    f32x4 accA0 = {bA0, bA0, bA0, bA0};
    f32x4 accA1 = {bA1, bA1, bA1, bA1};
    f32x4 accB0 = {0.f, 0.f, 0.f, 0.f};
    f32x4 accB1 = {0.f, 0.f, 0.f, 0.f};

    accA0 = __builtin_amdgcn_mfma_f32_16x16x32_bf16(a0, Bf[0][0][0], accA0, 0, 0, 0);
    accA0 = __builtin_amdgcn_mfma_f32_16x16x32_bf16(a1, Bf[0][0][1], accA0, 0, 0, 0);
    accA1 = __builtin_amdgcn_mfma_f32_16x16x32_bf16(a0, Bf[0][1][0], accA1, 0, 0, 0);
    accA1 = __builtin_amdgcn_mfma_f32_16x16x32_bf16(a1, Bf[0][1][1], accA1, 0, 0, 0);
    accB0 = __builtin_amdgcn_mfma_f32_16x16x32_bf16(a0, Bf[1][0][0], accB0, 0, 0, 0);
    accB0 = __builtin_amdgcn_mfma_f32_16x16x32_bf16(a1, Bf[1][0][1], accB0, 0, 0, 0);
    accB1 = __builtin_amdgcn_mfma_f32_16x16x32_bf16(a0, Bf[1][1][0], accB1, 0, 0, 0);
    accB1 = __builtin_amdgcn_mfma_f32_16x16x32_bf16(a1, Bf[1][1][1], accB1, 0, 0, 0);

#pragma unroll
    for (int j = 0; j < 4; ++j) {
        const long long node = base + g * 4 + j;
        if (node < N) {
            ya[node * 32 + n]      = q8(accA0[j]);
            ya[node * 32 + 16 + n] = q8(accA1[j]);
            yb[node * 32 + n]      = q8(accB0[j]);
            yb[node * 32 + 16 + n] = q8(accB1[j]);
        }
    }
}

// ---------------- main: per-edge fused layers 1(add)+2(MFMA)+3 -------------
template<bool EXACT>
__global__ __launch_bounds__(256, 8) void edge_mlp_v6(
    const char* __restrict__ ya, const char* __restrict__ yb,
    const int* __restrict__ ei,
    const float* __restrict__ W2, const float* __restrict__ b2,
    const float* __restrict__ W3, const float* __restrict__ b3,
    const float* __restrict__ temp,
    float* __restrict__ out, int E)
{
    const int t = threadIdx.x;
    const int w = t >> 6, l = t & 63, n = l & 15, g = l >> 4;

    // W2 as the A operand: lane (g,n) elem j = W2[row n][k g*8+j]
    const short8v W2f = conv8(W2 + n * 32 + g * 8);
    const f32x4 b2v4 = *(const f32x4*)(b2 + g * 4);
    const f32x4 w3v4 = *(const f32x4*)(W3 + g * 4);
    const float b3v  = b3[0];
    const float invT = 1.0f / temp[0];

    const int eb = blockIdx.x * 256 + w * 64;

    // hoisted index loads (streamed once -> nontemporal, don't evict tables)
    int rn_[4], cn_[4];
#pragma unroll
    for (int it = 0; it < 4; ++it) {
        if constexpr (EXACT) {
            rn_[it] = __builtin_nontemporal_load(ei + (eb + it * 16 + n));
            cn_[it] = __builtin_nontemporal_load(ei + E + (eb + it * 16 + n));
        } else {
            int e  = eb + it * 16 + n;
            int ec = (e < E) ? e : (E - 1);
            rn_[it] = ei[ec];
            cn_[it] = ei[(size_t)E + ec];
        }
    }

    // all 8 gathers issued up-front (8 B/lane; normal caching - keep in L2)
    char8v qa[4], qb[4];
#pragma unroll
    for (int it = 0; it < 4; ++it) {
        qa[it] = *(const char8v*)(ya + (rn_[it] * 32 + g * 8));
        qb[it] = *(const char8v*)(yb + (cn_[it] * 32 + g * 8));
    }

#pragma unroll
    for (int it = 0; it < 4; ++it) {
        const int base = eb + it * 16;

        // h1 = relu((qa+qb) * s); lane (g,n) elem j = h1[edge n][ch g*8+j]
        short8v hB;
#pragma unroll
        for (int j = 0; j < 8; ++j) {
            const int   si = (int)qa[it][j] + (int)qb[it][j];
            const float h  = fmaxf((float)si * QDEQ, 0.0f);
            hB[j] = (short)f32_bf16(h);
        }

        // layer 2 swapped: C[row=out_ch][col=edge]; lane (g,n): C[g*4+j][n]
        f32x4 acc2 = {0.f, 0.f, 0.f, 0.f};
        acc2 = __builtin_amdgcn_mfma_f32_16x16x32_bf16(W2f, hB, acc2, 0, 0, 0);

        // layer 3: partial over this lane's 4 channels, then reduce over g
        float s = 0.0f;
#pragma unroll
        for (int j = 0; j < 4; ++j)
            s += w3v4[j] * fmaxf(acc2[j] + b2v4[j], 0.0f);
        s += __shfl_xor(s, 16);
        s += __shfl_xor(s, 32);

        if (l < 16) {
            const int eo = base + l;
            const float ew = 1.0f / (1.0f + __expf(-(s + b3v)));
            const float o  = 1.0f / (1.0f + __expf(-ew * invT));
            if constexpr (EXACT) {
                __builtin_nontemporal_store(o, out + eo);   // stream, no-alloc
            } else {
                if (eo < E) out[eo] = o;
            }
        }
    }
}

// ---------------- fallback (ws too small): direct per-edge path -------------
__global__ __launch_bounds__(256, 4) void edge_mlp_direct(
    const float* __restrict__ x, const int* __restrict__ ei,
    const float* __restrict__ W1, const float* __restrict__ b1,
    const float* __restrict__ W2, const float* __restrict__ b2,
    const float* __restrict__ W3, const float* __restrict__ b3,
    const float* __restrict__ temp,
    float* __restrict__ out, int E)
{
    __shared__ short h1lds[4][16 * 40];
    const int t = threadIdx.x;
    const int w = t >> 6, l = t & 63, n = l & 15, g = l >> 4;

    short8v B1f[2][4];
#pragma unroll
    for (int nt = 0; nt < 2; ++nt)
#pragma unroll
        for (int q = 0; q < 4; ++q)
            B1f[nt][q] = conv8(W1 + ((nt * 16 + n) * 128 + q * 32 + g * 8));
    const short8v B2f = conv8(W2 + n * 32 + g * 8);

    const float b1v0 = b1[n], b1v1 = b1[16 + n];
    const float b2v = b2[n], w3v = W3[n], b3v = b3[0];
    const float invT = 1.0f / temp[0];

    short* hl = &h1lds[w][0];
    const long long eb = (long long)blockIdx.x * 256 + (long long)w * 64;

    for (int it = 0; it < 4; ++it) {
        const long long base = eb + it * 16;
        if (base >= E) break;
        long long e  = base + n;
        long long ec = (e < E) ? e : (long long)(E - 1);
        const int rn = ei[ec];
        const int cn = ei[(size_t)E + ec];

        f32x4 acc0 = {0.f,0.f,0.f,0.f}, acc1 = {0.f,0.f,0.f,0.f};
#pragma unroll
        for (int q = 0; q < 4; ++q) {
            const int node = (q < 2) ? rn : cn;
            const int elem = ((q & 1) * 32) + g * 8;
            short8v a = conv8(x + ((long long)node * 64 + elem));
            acc0 = __builtin_amdgcn_mfma_f32_16x16x32_bf16(a, B1f[0][q], acc0, 0, 0, 0);
            acc1 = __builtin_amdgcn_mfma_f32_16x16x32_bf16(a, B1f[1][q], acc1, 0, 0, 0);
        }
#pragma unroll
        for (int j = 0; j < 4; ++j) {
            const int m = g * 4 + j;
            hl[m * 40 + n]      = (short)f32_bf16(fmaxf(acc0[j] + b1v0, 0.f));
            hl[m * 40 + 16 + n] = (short)f32_bf16(fmaxf(acc1[j] + b1v1, 0.f));
        }
        const short8v a2 = *(const short8v*)(hl + ((l & 15) * 40 + g * 8));
        f32x4 acc2 = {0.f,0.f,0.f,0.f};
        acc2 = __builtin_amdgcn_mfma_f32_16x16x32_bf16(a2, B2f, acc2, 0, 0, 0);

        float p0 = w3v * fmaxf(acc2[0] + b2v, 0.f);
        float p1 = w3v * fmaxf(acc2[1] + b2v, 0.f);
        float p2 = w3v * fmaxf(acc2[2] + b2v, 0.f);
        float p3 = w3v * fmaxf(acc2[3] + b2v, 0.f);
#pragma unroll
        for (int mask = 1; mask <= 8; mask <<= 1) {
            p0 += __shfl_xor(p0, mask, 16);
            p1 += __shfl_xor(p1, mask, 16);
            p2 += __shfl_xor(p2, mask, 16);
            p3 += __shfl_xor(p3, mask, 16);
        }
        if (n < 4) {
            const float pv = (n == 0) ? p0 : ((n == 1) ? p1 : ((n == 2) ? p2 : p3));
            const float ew = 1.0f / (1.0f + __expf(-(pv + b3v)));
            const float o  = 1.0f / (1.0f + __expf(-ew * invT));
            const long long eo = base + g * 4 + n;
            if (eo < E) out[eo] = o;
        }
    }
}

extern "C" void kernel_launch(void* const* d_in, const int* in_sizes, int n_in,
                              void* d_out, int out_size, void* d_ws, size_t ws_size,
                              hipStream_t stream)
{
    const float* x    = (const float*)d_in[0];
    const int*   ei   = (const int*)  d_in[1];
    const float* W1   = (const float*)d_in[2];
    const float* b1   = (const float*)d_in[3];
    const float* W2   = (const float*)d_in[4];
    const float* b2   = (const float*)d_in[5];
    const float* W3   = (const float*)d_in[6];
    const float* b3   = (const float*)d_in[7];
    const float* temp = (const float*)d_in[8];
    float* out = (float*)d_out;

    const int E = in_sizes[1] / 2;        // edge_index is [2, E]
    const int N = in_sizes[0] / 64;       // nodes
    const size_t need = (size_t)N * 64;   // ya + yb, int8 [N][32] each

    const int eblocks = (E + 255) / 256;
    if (ws_size >= need) {
        char* yat = (char*)d_ws;
        char* ybt = yat + (size_t)N * 32;
        precompute_y<<<(N + 63) / 64, 256, 0, stream>>>(x, W1, b1, yat, ybt, N);
        if (E % 256 == 0) {
            edge_mlp_v6<true><<<eblocks, 256, 0, stream>>>(
                yat, ybt, ei, W2, b2, W3, b3, temp, out, E);
        } else {
            edge_mlp_v6<false><<<eblocks, 256, 0, stream>>>(
                yat, ybt, ei, W2, b2, W3, b3, temp, out, E);
        }
    } else {
        edge_mlp_direct<<<eblocks, 256, 0, stream>>>(x, ei, W1, b1, W2, b2,
                                                     W3, b3, temp, out, E);
    }
}